// Round 1
// baseline (4683.924 us; speedup 1.0000x reference)
//
#include <hip/hip_runtime.h>
#include <hip/hip_bf16.h>
#include <stdint.h>

// Problem dims
#define BB 64     // batch
#define SS 512    // seq len
#define HH 512    // hidden
#define DD 300    // embed dim
#define DP 320    // embed dim padded to K%32==0

typedef __attribute__((ext_vector_type(8))) short short8;  // 8 x bf16
typedef __attribute__((ext_vector_type(4))) float f32x4;

__device__ __forceinline__ unsigned short f2bf(float f) {
  unsigned u = __builtin_bit_cast(unsigned, f);
  u += 0x7fffu + ((u >> 16) & 1u);       // RNE
  return (unsigned short)(u >> 16);
}
__device__ __forceinline__ float sigm(float x) { return 1.f / (1.f + __expf(-x)); }
__device__ __forceinline__ float tanh_f(float x) {
  float t = __expf(-2.f * fabsf(x));
  float r = (1.f - t) / (1.f + t);
  return x < 0.f ? -r : r;
}

// ---------------- workspace layout (bytes) ----------------
#define OFF_FLAGS 0u          // 128 flags, 64B spaced -> 8192
#define OFF_H1    8192u       // h1 ring [2][64][512] bf16 -> 131072
#define OFF_H2    139264u     // h2 ring [2][64][512] bf16 -> 131072
#define OFF_C2    270336u     // c2 [64][512] f32 -> 131072
#define OFF_XE    401408u     // xe [512][64][320] bf16 -> 20971520
#define OFF_W0    21372928u   // Wp0 [2048][832] bf16 -> 3407872
#define OFF_W1    24780800u   // Wp1 [2048][1024] bf16 -> 4194304
#define OFF_B0    28975104u   // bias0p [2048] f32
#define OFF_B1    28983296u   // bias1p [2048] f32
#define MEMSET_BYTES 270336u  // flags + both rings

// ---------------- weight prep ----------------
// Row reorder: global row grow = lblk*32 + l, l in [0,32): gate = l>>3 (i,f,g,o),
// h = lblk*8 + (l&7), orig = gate*512 + h.
// Wp0 row: [ W_hh0[orig][0:512] | W_ih0[orig][0:300] | 0 pad to 832 ]   (A = [h1_prev | x_t])
// Wp1 row: [ W_ih1[orig][0:512] | W_hh1[orig][0:512] ]                  (A = [h1_t | h2_prev])
__global__ void prep_weights(const float* __restrict__ Wih0, const float* __restrict__ Whh0,
                             const float* __restrict__ bih0, const float* __restrict__ bhh0,
                             const float* __restrict__ Wih1, const float* __restrict__ Whh1,
                             const float* __restrict__ bih1, const float* __restrict__ bhh1,
                             unsigned short* __restrict__ Wp0, unsigned short* __restrict__ Wp1,
                             float* __restrict__ b0p, float* __restrict__ b1p)
{
  int idx = blockIdx.x * 256 + threadIdx.x;   // over 2048*1024
  int grow = idx >> 10;
  int k1 = idx & 1023;
  int l = grow & 31;
  int lb = grow >> 5;
  int gate = l >> 3;
  int orig = gate * 512 + lb * 8 + (l & 7);
  float v1 = (k1 < 512) ? Wih1[orig * 512 + k1] : Whh1[orig * 512 + (k1 - 512)];
  Wp1[idx] = f2bf(v1);
  if (k1 < 832) {
    float v0;
    if (k1 < 512)      v0 = Whh0[orig * 512 + k1];
    else if (k1 < 812) v0 = Wih0[orig * 300 + (k1 - 512)];
    else               v0 = 0.f;
    Wp0[grow * 832 + k1] = f2bf(v0);
  }
  if (k1 == 0) {
    b0p[grow] = bih0[orig] + bhh0[orig];
    b1p[grow] = bih1[orig] + bhh1[orig];
  }
}

// ---------------- embedding gather (time-major, padded, bf16) ----------------
__global__ void gather_xe(const int* __restrict__ x, const float* __restrict__ emb,
                          unsigned short* __restrict__ xe)
{
  int idx = blockIdx.x * 256 + threadIdx.x;   // SS*BB*DP = 10485760
  int dk = idx % DP;
  int rem = idx / DP;
  int b = rem % BB;
  int t = rem / BB;
  int tok = x[b * SS + t];
  float v = (dk < DD) ? emb[(size_t)tok * DD + dk] : 0.f;
  xe[idx] = f2bf(v);
}

// ---------------- persistent pipelined 2-layer scan ----------------
// Grid: 128 blocks x 512 thr. blk<64 -> layer0 (h-slice blk*8..+8), else layer1.
// At iteration k: L0 does step k (k<512), L1 does step k-1 (k>=1). One inter-block
// barrier per iteration (513 iterations, 512 barriers).
// Per block: 32 gate rows [i(8) f(8) g(8) o(8)] = 2 MFMA N-tiles.
// Wave (of 8) = (mtile = w&3, khalf = w>>2). W fragments persistent in VGPRs.
template<bool IS_L0>
__device__ __forceinline__ void scan_body(
    int blk,
    const unsigned short* __restrict__ xe,
    const unsigned short* __restrict__ Wp,
    const float* __restrict__ biasP,
    unsigned short* __restrict__ h1r,
    unsigned short* __restrict__ h2r,
    float* __restrict__ c2,
    unsigned int* flags,
    float (&gl)[2][64][36], float (&bias_sm)[32])
{
  constexpr int K  = IS_L0 ? 832 : 1024;
  constexpr int NK = IS_L0 ? 13 : 16;      // kblks per khalf
  constexpr int QS = IS_L0 ? 416 : 512;    // khalf size
  constexpr int SB = IS_L0 ? DP : HH;      // row stride of second A source

  const int tid  = threadIdx.x;
  const int wave = tid >> 6;
  const int lane = tid & 63;
  const int lrow = lane & 15;
  const int lk   = lane >> 4;
  const int m    = wave & 3;
  const int q    = wave >> 2;
  const int lblk = IS_L0 ? blk : blk - 64;
  const int h0   = lblk * 8;
  const int qbase = q * QS;

  if (tid < 32) bias_sm[tid] = biasP[lblk * 32 + tid];

  // Persistent W fragments: lane holds rows (lblk*32 + nt*16 + lrow), k = qbase + j*32 + lk*8 .. +8
  short8 Bf0[NK], Bf1[NK];
  {
    const unsigned short* wr0 = Wp + (size_t)(lblk * 32 + lrow) * K + qbase + lk * 8;
    const unsigned short* wr1 = wr0 + (size_t)16 * K;
    #pragma unroll
    for (int j = 0; j < NK; ++j) {
      Bf0[j] = *(const short8*)(wr0 + j * 32);
      Bf1[j] = *(const short8*)(wr1 + j * 32);
    }
  }

  float creg = 0.f;                 // cell state: 1 cell per thread
  const int pb = tid >> 3;          // pointwise batch
  const int ph = tid & 7;           // pointwise h-offset
  const int batch = m * 16 + lrow;  // A-fragment row

  for (int k = 0;; ++k) {
    const bool active = IS_L0 ? (k < 512) : (k >= 1);
    if (active) {
      const int t = IS_L0 ? k : k - 1;
      // h1 read slot (k+1)&1 for both layers; L0 writes h1 slot k&1.
      // L1 reads h2 slot k&1, writes h2 slot (k+1)&1.
      const unsigned short* srcA = h1r + (size_t)((k + 1) & 1) * (BB * HH);
      const unsigned short* srcB = IS_L0 ? (xe + (size_t)t * BB * DP)
                                         : (h2r + (size_t)(k & 1) * (BB * HH));
      short8 a[NK];
      #pragma unroll
      for (int j = 0; j < NK; ++j) {
        const int kb = qbase + j * 32;                 // lane-uniform
        const unsigned short* p = (kb < 512)
            ? (srcA + (size_t)batch * HH + kb + lk * 8)
            : (srcB + (size_t)batch * SB + (kb - 512) + lk * 8);
        a[j] = *(const short8*)p;
      }
      f32x4 acc0 = {0.f, 0.f, 0.f, 0.f};
      f32x4 acc1 = {0.f, 0.f, 0.f, 0.f};
      #pragma unroll
      for (int j = 0; j < NK; ++j) {
        acc0 = __builtin_amdgcn_mfma_f32_16x16x32_bf16(a[j], Bf0[j], acc0, 0, 0, 0);
        acc1 = __builtin_amdgcn_mfma_f32_16x16x32_bf16(a[j], Bf1[j], acc1, 0, 0, 0);
      }
      // Stage gates: D row = (lane>>4)*4+reg -> batch, D col = lane&15 -> gate row
      #pragma unroll
      for (int r = 0; r < 4; ++r) {
        const int bb = m * 16 + lk * 4 + r;
        gl[q][bb][lrow]      = acc0[r];
        gl[q][bb][16 + lrow] = acc1[r];
      }
      __syncthreads();
      {
        float gi = gl[0][pb][ph]      + gl[1][pb][ph]      + bias_sm[ph];
        float gf = gl[0][pb][8 + ph]  + gl[1][pb][8 + ph]  + bias_sm[8 + ph];
        float gg = gl[0][pb][16 + ph] + gl[1][pb][16 + ph] + bias_sm[16 + ph];
        float go = gl[0][pb][24 + ph] + gl[1][pb][24 + ph] + bias_sm[24 + ph];
        float iv = sigm(gi), fv = sigm(gf), ov = sigm(go), gv = tanh_f(gg);
        creg = fv * creg + iv * gv;
        float hv = ov * tanh_f(creg);
        if (IS_L0) {
          h1r[(size_t)(k & 1) * (BB * HH) + pb * HH + h0 + ph] = f2bf(hv);
        } else {
          h2r[(size_t)((k + 1) & 1) * (BB * HH) + pb * HH + h0 + ph] = f2bf(hv);
          if (k == 512) c2[pb * HH + h0 + ph] = creg;
        }
      }
    }
    if (k == 512) break;
    // -------- inter-block barrier --------
    __syncthreads();
    if (tid == 0)
      __hip_atomic_store(&flags[blk * 16], (unsigned)(k + 1), __ATOMIC_RELEASE,
                         __HIP_MEMORY_SCOPE_AGENT);
    if (wave == 0) {
      const unsigned tgt = (unsigned)(k + 1);
      int guard = 0;
      for (;;) {
        unsigned v0 = __hip_atomic_load(&flags[lane * 16], __ATOMIC_RELAXED,
                                        __HIP_MEMORY_SCOPE_AGENT);
        unsigned v1 = __hip_atomic_load(&flags[(64 + lane) * 16], __ATOMIC_RELAXED,
                                        __HIP_MEMORY_SCOPE_AGENT);
        if (__all((v0 >= tgt) && (v1 >= tgt))) break;
        if (++guard > (1 << 15)) break;   // liveness insurance (never hit when healthy)
      }
      __builtin_amdgcn_fence(__ATOMIC_ACQUIRE, "agent");
    }
    __syncthreads();
  }
}

__global__ void __launch_bounds__(512, 2)
lstm_scan(const unsigned short* __restrict__ xe,
          const unsigned short* __restrict__ Wp0,
          const unsigned short* __restrict__ Wp1,
          const float* __restrict__ b0p, const float* __restrict__ b1p,
          unsigned short* __restrict__ h1r, unsigned short* __restrict__ h2r,
          float* __restrict__ c2, unsigned int* __restrict__ flags)
{
  __shared__ float gl[2][64][36];
  __shared__ float bias_sm[32];
  const int blk = blockIdx.x;
  if (blk < 64) scan_body<true >(blk, xe, Wp0, b0p, h1r, h2r, c2, flags, gl, bias_sm);
  else          scan_body<false>(blk, xe, Wp1, b1p, h1r, h2r, c2, flags, gl, bias_sm);
}

// ---------------- final projection: out = c2 @ Wout^T + bout ----------------
__global__ void outproj(const float* __restrict__ c2, const float* __restrict__ Wout,
                        const float* __restrict__ bout, float* __restrict__ out)
{
  int t = threadIdx.x;
  if (t >= 640) return;
  int b = t / 10, l = t % 10;
  float s = bout[l];
  #pragma unroll 8
  for (int h = 0; h < 512; ++h) s += c2[b * 512 + h] * Wout[l * 512 + h];
  out[b * 10 + l] = s;
}

extern "C" void kernel_launch(void* const* d_in, const int* in_sizes, int n_in,
                              void* d_out, int out_size, void* d_ws, size_t ws_size,
                              hipStream_t stream) {
  (void)in_sizes; (void)n_in; (void)out_size; (void)ws_size;
  const int*   x    = (const int*)  d_in[0];
  const float* emb  = (const float*)d_in[1];
  const float* Wih0 = (const float*)d_in[2];
  const float* Whh0 = (const float*)d_in[3];
  const float* bih0 = (const float*)d_in[4];
  const float* bhh0 = (const float*)d_in[5];
  const float* Wih1 = (const float*)d_in[6];
  const float* Whh1 = (const float*)d_in[7];
  const float* bih1 = (const float*)d_in[8];
  const float* bhh1 = (const float*)d_in[9];
  const float* Wout = (const float*)d_in[10];
  const float* bout = (const float*)d_in[11];
  float* out = (float*)d_out;

  char* ws = (char*)d_ws;
  unsigned int*   flags = (unsigned int*)  (ws + OFF_FLAGS);
  unsigned short* h1r   = (unsigned short*)(ws + OFF_H1);
  unsigned short* h2r   = (unsigned short*)(ws + OFF_H2);
  float*          c2    = (float*)         (ws + OFF_C2);
  unsigned short* xe    = (unsigned short*)(ws + OFF_XE);
  unsigned short* Wp0   = (unsigned short*)(ws + OFF_W0);
  unsigned short* Wp1   = (unsigned short*)(ws + OFF_W1);
  float*          b0p   = (float*)         (ws + OFF_B0);
  float*          b1p   = (float*)         (ws + OFF_B1);

  hipMemsetAsync(ws, 0, MEMSET_BYTES, stream);   // flags + h rings = 0
  prep_weights<<<8192, 256, 0, stream>>>(Wih0, Whh0, bih0, bhh0, Wih1, Whh1, bih1, bhh1,
                                         Wp0, Wp1, b0p, b1p);
  gather_xe<<<40960, 256, 0, stream>>>(x, emb, xe);
  lstm_scan<<<128, 512, 0, stream>>>(xe, Wp0, Wp1, b0p, b1p, h1r, h2r, c2, flags);
  outproj<<<1, 640, 0, stream>>>(c2, Wout, bout, out);
}